// Round 2
// baseline (188.973 us; speedup 1.0000x reference)
//
#include <hip/hip_runtime.h>
#include <hip/hip_bf16.h>
#include <math.h>

#define T_ 16
#define B_ 16
#define N_ 256
#define H_ 512
#define L_ 64
#define K_ 8
#define SCALE 0.04419417382415922f   // THETA / sqrt(512)

// ============================================================================
// Kernel 0: q_t[b][h][t] = q[t][0][b][h]   (512 KB, makes q-loads wave-uniform
// AND t-contiguous so the score kernel reads q with scalar loads)
// ============================================================================
__global__ __launch_bounds__(256) void transpose_q_kernel(
    const float* __restrict__ q, float* __restrict__ q_t) {
  const int tid = blockIdx.x * 256 + threadIdx.x;  // 0..131071, write-coalesced
  const int b = tid >> 13;
  const int h = (tid >> 4) & (H_ - 1);
  const int t = tid & 15;
  q_t[tid] = q[((size_t)t * B_ + b) * H_ + h];
}

// ============================================================================
// Kernel 1: one WAVE per (b,n) tile; lane = j (key row).  Each lane streams
// its own 2 KB key row and accumulates 16 full dot products (one per t) with
// wave-uniform q operands -> no per-dot cross-lane reduction at all.
// Epilogue: 16 shfl-max butterflies (max over j) + 16 scalar stores.
// ============================================================================
__device__ __forceinline__ void fma16(const float4* __restrict__ qv, float kx,
                                      float* __restrict__ acc) {
  const float4 qa = qv[0], qb = qv[1], qc = qv[2], qd = qv[3];
  acc[0] = fmaf(qa.x, kx, acc[0]);
  acc[1] = fmaf(qa.y, kx, acc[1]);
  acc[2] = fmaf(qa.z, kx, acc[2]);
  acc[3] = fmaf(qa.w, kx, acc[3]);
  acc[4] = fmaf(qb.x, kx, acc[4]);
  acc[5] = fmaf(qb.y, kx, acc[5]);
  acc[6] = fmaf(qb.z, kx, acc[6]);
  acc[7] = fmaf(qb.w, kx, acc[7]);
  acc[8] = fmaf(qc.x, kx, acc[8]);
  acc[9] = fmaf(qc.y, kx, acc[9]);
  acc[10] = fmaf(qc.z, kx, acc[10]);
  acc[11] = fmaf(qc.w, kx, acc[11]);
  acc[12] = fmaf(qd.x, kx, acc[12]);
  acc[13] = fmaf(qd.y, kx, acc[13]);
  acc[14] = fmaf(qd.z, kx, acc[14]);
  acc[15] = fmaf(qd.w, kx, acc[15]);
}

// process one 4-h chunk: k4 holds k[j][h0..h0+3], qv points at q_t[b][h0][0]
__device__ __forceinline__ void chunk4(const float4 k4,
                                       const float4* __restrict__ qv,
                                       float* __restrict__ acc) {
  fma16(qv + 0, k4.x, acc);
  fma16(qv + 4, k4.y, acc);
  fma16(qv + 8, k4.z, acc);
  fma16(qv + 12, k4.w, acc);
}

__global__ __launch_bounds__(256, 4) void score_kernel(
    const float* __restrict__ q_t, const float* __restrict__ keys,
    float* __restrict__ scores) {
  const int bid  = blockIdx.x;        // 0..1023
  const int b    = bid >> 6;          // block-uniform
  const int wave = threadIdx.x >> 6;
  const int lane = threadIdx.x & 63;  // = j
  const int n    = ((bid & 63) << 2) | wave;

  const float* __restrict__ qb = q_t + ((size_t)b << 13);  // wave-uniform base
  const float* __restrict__ kr =
      keys + ((size_t)n * B_ + b) * (size_t)(L_ * H_) + (size_t)lane * H_;

  float acc[T_];
#pragma unroll
  for (int t = 0; t < T_; ++t) acc[t] = 0.0f;

  // depth-2 chunk prefetch of this lane's key row
  float4 kq0 = *(const float4*)(kr + 0);
  float4 kq1 = *(const float4*)(kr + 4);

  for (int c2 = 0; c2 < 64; ++c2) {  // two 4-h chunks per iteration
    const float4 ka = kq0;
    const float4 kb4 = kq1;
    const int pf = (c2 < 63) ? (8 * c2 + 8) : 0;  // stay in-bounds at the tail
    kq0 = *(const float4*)(kr + pf);
    kq1 = *(const float4*)(kr + pf + 4);
    const float4* qv = (const float4*)(qb + (c2 << 7));  // q_t[b][8*c2][0]
    chunk4(ka, qv, acc);
    chunk4(kb4, qv + 16, acc);
  }

  // score[t] = max over j (= lanes) ; write raw scores
#pragma unroll
  for (int t = 0; t < T_; ++t) {
    float m = acc[t];
#pragma unroll
    for (int d = 1; d < 64; d <<= 1) m = fmaxf(m, __shfl_xor(m, d));
    if (lane == t) scores[(size_t)t * (B_ * N_) + b * N_ + n] = m;
  }
}

// ============================================================================
// Kernel 2: one wave per (t,b) row.  In-place softmax over N=256, then top-8
// (value desc, index asc on ties).  Indices written as float values.
// ============================================================================
__global__ __launch_bounds__(256) void softmax_topk_kernel(
    float* __restrict__ att, float* __restrict__ out_idx) {
  const int row  = blockIdx.x * 4 + (threadIdx.x >> 6);  // t*B + b
  const int lane = threadIdx.x & 63;

  float* s = att + (size_t)row * N_;
  const float4 v4 = *(const float4*)(s + 4 * lane);
  const float v[4] = {v4.x, v4.y, v4.z, v4.w};

  float m = fmaxf(fmaxf(v[0], v[1]), fmaxf(v[2], v[3]));
#pragma unroll
  for (int d = 1; d < 64; d <<= 1) m = fmaxf(m, __shfl_xor(m, d));

  float p[4];
#pragma unroll
  for (int e = 0; e < 4; ++e) p[e] = expf(SCALE * (v[e] - m));

  float sum = p[0] + p[1] + p[2] + p[3];
#pragma unroll
  for (int d = 1; d < 64; d <<= 1) sum += __shfl_xor(sum, d);
  const float inv = 1.0f / sum;

  float a[4];
#pragma unroll
  for (int e = 0; e < 4; ++e) a[e] = p[e] * inv;

  *(float4*)(s + 4 * lane) = make_float4(a[0], a[1], a[2], a[3]);

  float w[4] = {a[0], a[1], a[2], a[3]};
  for (int kk = 0; kk < K_; ++kk) {
    float bv = w[0];
    int bn = 4 * lane;
#pragma unroll
    for (int e = 1; e < 4; ++e) {
      if (w[e] > bv) { bv = w[e]; bn = 4 * lane + e; }
    }
#pragma unroll
    for (int d = 1; d < 64; d <<= 1) {
      const float ov = __shfl_xor(bv, d);
      const int on = __shfl_xor(bn, d);
      if (ov > bv || (ov == bv && on < bn)) { bv = ov; bn = on; }
    }
    if (lane == 0) out_idx[kk * (T_ * B_) + row] = (float)bn;  // (k,T,B)
#pragma unroll
    for (int e = 0; e < 4; ++e)
      if (4 * lane + e == bn) w[e] = -1.0f;
  }
}

extern "C" void kernel_launch(void* const* d_in, const int* in_sizes, int n_in,
                              void* d_out, int out_size, void* d_ws,
                              size_t ws_size, hipStream_t stream) {
  const float* q    = (const float*)d_in[0];   // (T,1,B,H) fp32
  const float* keys = (const float*)d_in[1];   // (N,B,L*H) fp32
  float* out = (float*)d_out;
  float* att = out;                 // 65536 floats: raw scores -> attention
  float* idx = out + T_ * B_ * N_;  // 2048 floats: (k,T,B) indices as floats
  float* q_t = (float*)d_ws;        // 131072 floats = 512 KB scratch

  transpose_q_kernel<<<(T_ * B_ * H_) / 256, 256, 0, stream>>>(q, q_t);
  score_kernel<<<B_ * (N_ / 4), 256, 0, stream>>>(q_t, keys, att);
  softmax_topk_kernel<<<(T_ * B_) / 4, 256, 0, stream>>>(att, idx);
}